// Round 11
// baseline (327.540 us; speedup 1.0000x reference)
//
#include <hip/hip_runtime.h>
#include <hip/hip_fp16.h>

// ResidualDenoiser: 4 chained GEMMs + BN/ReLU + ragged segment softmax.
// Activations live in one persistent fp16 buffer H[8192][3328] laid out
// [A3 | A2 | A1 | A0=x] so each layer's concatenated input is H + colOff.
//   layer0: in H+3072 (K= 256) -> out cols 2048:3072  (+ converts Wh1)
//   layer1: in H+2048 (K=1280) -> out cols 1024:2048  (+ converts Wh2)
//   layer2: in H+1024 (K=2304) -> out cols    0:1024  (+ converts Wh3)
//   layer3: in H+0    (K=3328) -> splitK=4; partials to workspace (no
//           atomics), softmax dispatch sums partials + bias.
// LESSONS:
//  R4-R6: in-kernel cross-block sync costs 300-450 us — keep dispatches.
//  R7-R12 (6 failed/neutral RE-SCHEDULINGS of the GEMM core): barrier
//    topology / counted vmcnt / setprio / wave re-partition / addr
//    precompute all neutral-or-worse. MfmaUtil pinned 33%.
//  R14 (WIN, 243->229): gemm_out atomics -> splitK partials + fused sum.
//  R15 (FAILED): converter as 64-block y-slice = latency-bound 50us.
//  R16 (NULL): converter as 512-block tail — conversion traffic is
//    BW-serial wherever it runs; tails offset prep savings exactly.
//  R17 (this round, NEW-EVIDENCE core change — removes work, does not
//    re-schedule): cycle budget per CU-BK128-iter = LDS-rd 2048 + LDS-wr
//    750 + conflicts ~1000 + MFMA 1318 + barrier ~650; B tile is half the
//    LDS traffic and needs none of it (each B elem consumed by exactly 1
//    wave; fragment pattern is 16 rows x 64B contiguous per wave-load).
//    => STREAM B GLOBAL->REG, delete Blds entirely. XCD swizzle y=bid&7
//    keeps each col-block's W panel (<=590KB) resident in its XCD's L2
//    across the 64 row-block re-reads. A path byte-identical to R0.
//    B drains at the same __syncthreads vmcnt(0) that drains A staging.

#define LDH 3328
#define NROWS 8192

typedef _Float16 f16x8 __attribute__((ext_vector_type(8)));
typedef _Float16 f16x4 __attribute__((ext_vector_type(4)));
typedef float f32x4 __attribute__((ext_vector_type(4)));

__constant__ int c_bnd[11] = {0, 2, 5, 10, 18, 31, 52, 86, 141, 230, 256};

// async global->LDS, 16B per lane; LDS dest is wave-uniform base + lane*16.
__device__ __forceinline__ void async_cp16(const _Float16* g, _Float16* l) {
  __builtin_amdgcn_global_load_lds(
      (__attribute__((address_space(1))) void*)g,
      (__attribute__((address_space(3))) void*)l, 16, 0, 0);
}

__device__ __forceinline__ _Float16 f2h(float f) { return (_Float16)f; }

// ---------------------------------------------------------------------------
// prep (slim): W0 fp32->fp16, x staged into H; out=bias on fallback path.
__global__ void prep_kernel(const float* __restrict__ w0,
                            const float* __restrict__ x,
                            const float* __restrict__ b3,
                            _Float16* __restrict__ d0,
                            _Float16* __restrict__ H, float* __restrict__ out,
                            int n0, int n1, int n2) {
  int i = blockIdx.x * blockDim.x + threadIdx.x;
  if (i >= n2) return;
  if (i >= n1) {  // out[8192][256] = broadcast bias b3 (fallback path)
    const int j = i - n1;
    const int c = (j & 63) * 4;
    *(float4*)&out[(size_t)j * 4] = *(const float4*)&b3[c];
    return;
  }
  if (i >= n0) {  // x[8192,256] -> H[:, 3072:3328]
    const int j = i - n0;
    const int row = j >> 6;
    const int c = (j & 63) * 4;
    const float4 v = *(const float4*)&x[(size_t)j * 4];
    f16x4 h = {f2h(v.x), f2h(v.y), f2h(v.z), f2h(v.w)};
    *(f16x4*)&H[(size_t)row * LDH + 3072 + c] = h;
    return;
  }
  const float4 v = *(const float4*)&w0[(size_t)i * 4];
  f16x4 h = {f2h(v.x), f2h(v.y), f2h(v.z), f2h(v.w)};
  *(f16x4*)&d0[(size_t)i * 4] = h;
}

// ---------------------------------------------------------------------------
// Layers 0-2: C = relu(bn(A@W^T)) fp16. Grid 512 (1D): by=bid&7 (col0,
// XCD-pinned for W L2-residency), bx=bid>>3 (row0).
// A: R0-proven async_cp16 staging into Alds[128x128] (XOR swizzle on the
// GLOBAL source address, LDS dest linear), 2-sync skeleton.
// B: streamed global->reg, 16x f16x8 per lane per BK128 iter; lanes
// (fr,q) of a wave cover 16 rows x 64 contiguous bytes per load. Drained
// by the same vmcnt(0) the staging barrier already pays.
// POST-EPILOGUE TAIL: 512 blocks grid-stride-convert next layer's weights.
__launch_bounds__(256, 2) __global__
void gemm_bn_kernel(const _Float16* __restrict__ A, int K,
                    const _Float16* __restrict__ W,
                    const float* __restrict__ bias,
                    const float* __restrict__ g, const float* __restrict__ be,
                    const float* __restrict__ rm,
                    const float* __restrict__ rv, _Float16* __restrict__ outH,
                    int outOff, const float* __restrict__ cvt_src,
                    _Float16* __restrict__ cvt_dst, int cvt_nf4) {
  __shared__ _Float16 Alds[128 * 128];  // 32 KB (A only; B streams in regs)

  const int tid = threadIdx.x;
  const int lane = tid & 63;
  const int wave = tid >> 6;          // 0..3
  const int wr = wave >> 1;           // 64-row half
  const int wc = wave & 1;            // 64-col half
  const int bid = blockIdx.x;
  const int row0 = (bid >> 3) * 128;  // M block
  const int col0 = (bid & 7) * 128;   // N block (XCD-pinned)
  // staging lane decomposition: each cp16 instr covers 4 rows x 16 chunks
  const int lr4 = lane >> 4;  // row within 4-row group
  const int sl = lane & 15;   // lds slot within row
  // fragment lane decomposition (16x16x32 MFMA)
  const int fr = lane & 15;  // m (A) / n (B) index
  const int q = lane >> 4;   // quad: k = q*8 + j

  // per-lane B base: row (col0 + wc*64 + fr), k-chunk q
  const _Float16* Wb = W + (size_t)(col0 + wc * 64 + fr) * K + q * 8;
  const size_t WrowT = (size_t)16 * K;  // t stride (16 rows)

  f32x4 acc[4][4] = {};

  for (int k0 = 0; k0 < K; k0 += 128) {
    __syncthreads();  // previous-iter consumers done before overwrite
#pragma unroll
    for (int it = 0; it < 8; ++it) {
      const int j = it * 4 + wave;     // instr id 0..31
      const int r = j * 4 + lr4;       // tile row 0..127
      const int gc = sl ^ (r & 7);     // global chunk fetched into slot sl
      async_cp16(A + (size_t)(row0 + r) * LDH + k0 + gc * 8, &Alds[j * 512]);
    }
    // B fragments for this K-tile, straight from global (L2-resident).
    f16x8 bv[4][4];
#pragma unroll
    for (int kq = 0; kq < 4; ++kq)
#pragma unroll
      for (int t = 0; t < 4; ++t)
        bv[kq][t] = *(const f16x8*)&Wb[(size_t)t * WrowT + k0 + kq * 32];
    __syncthreads();  // drains vmcnt: A staged (and B arrived)

#pragma unroll
    for (int kq = 0; kq < 4; ++kq) {
      f16x8 av[4];
#pragma unroll
      for (int t = 0; t < 4; ++t) {
        const int ra = wr * 64 + t * 16 + fr;
        av[t] =
            *(const f16x8*)&Alds[ra * 128 + (((kq * 4 + q) ^ (ra & 7)) * 8)];
      }
#pragma unroll
      for (int tm = 0; tm < 4; ++tm)
#pragma unroll
        for (int tn = 0; tn < 4; ++tn)
          acc[tm][tn] = __builtin_amdgcn_mfma_f32_16x16x32_f16(
              av[tm], bv[kq][tn], acc[tm][tn], 0, 0, 0);
    }
  }

  // Epilogue. C/D layout: col = lane&15, row = (lane>>4)*4 + reg.
#pragma unroll
  for (int tn = 0; tn < 4; ++tn) {
    const int n = col0 + wc * 64 + tn * 16 + fr;
    const float alpha = g[n] * rsqrtf(rv[n] + 1e-5f);
    const float beta = (bias[n] - rm[n]) * alpha + be[n];
#pragma unroll
    for (int tm = 0; tm < 4; ++tm) {
      const int rbase = row0 + wr * 64 + tm * 16 + q * 4;
#pragma unroll
      for (int r = 0; r < 4; ++r) {
        float v = acc[tm][tn][r] * alpha + beta;
        v = fmaxf(v, 0.0f);
        outH[(size_t)(rbase + r) * LDH + outOff + n] = f2h(v);
      }
    }
  }

  // Tail: convert next layer's weights across all 512 blocks.
  for (int i = bid * 256 + tid; i < cvt_nf4; i += 512 * 256) {
    const float4 v = *(const float4*)&cvt_src[(size_t)i * 4];
    f16x4 h = {f2h(v.x), f2h(v.y), f2h(v.z), f2h(v.w)};
    *(f16x4*)&cvt_dst[(size_t)i * 4] = h;
  }
}

// ---------------------------------------------------------------------------
// Layer 3, partials path: splitK=4, BK=64. Grid dim3(64,8): cb=by&1 (col
// tile), ks=by>>1. Plain stores into P[ks][8192][256] fp32 (no atomics).
__launch_bounds__(256, 4) __global__
void gemm_out_split(const _Float16* __restrict__ A,
                    const _Float16* __restrict__ W, float* __restrict__ P) {
  __shared__ _Float16 Alds[128 * 64];
  __shared__ _Float16 Blds[128 * 64];

  const int tid = threadIdx.x;
  const int lane = tid & 63;
  const int wave = tid >> 6;
  const int wr = wave >> 1;
  const int wc = wave & 1;
  const int row0 = blockIdx.x * 128;
  const int cb = blockIdx.y & 1;
  const int ks = blockIdx.y >> 1;
  const int col0 = cb * 128;
  const int k0b = ks * 832;
  const int k0e = k0b + 832;
  const int lr = lane >> 3;  // staging: 8 rows x 8 16B-chunks
  const int ls = lane & 7;
  const int lc = ls ^ lr;
  const int fr = lane & 15;
  const int q = lane >> 4;
  const int K = 3328;

  f32x4 acc[4][4] = {};

  for (int k0 = k0b; k0 < k0e; k0 += 64) {
    __syncthreads();
#pragma unroll
    for (int it = 0; it < 4; ++it) {
      const int rl = it * 32 + wave * 8;
      async_cp16(A + (size_t)(row0 + rl + lr) * LDH + k0 + lc * 8,
                 &Alds[rl * 64]);
      async_cp16(W + (size_t)(col0 + rl + lr) * K + k0 + lc * 8,
                 &Blds[rl * 64]);
    }
    __syncthreads();

#pragma unroll
    for (int kq = 0; kq < 2; ++kq) {
      f16x8 av[4], bv[4];
#pragma unroll
      for (int t = 0; t < 4; ++t) {
        const int ra = wr * 64 + t * 16 + fr;
        av[t] = *(const f16x8*)&Alds[ra * 64 + (((q + 4 * kq) ^ (ra & 7)) * 8)];
        const int rb = wc * 64 + t * 16 + fr;
        bv[t] = *(const f16x8*)&Blds[rb * 64 + (((q + 4 * kq) ^ (rb & 7)) * 8)];
      }
#pragma unroll
      for (int tm = 0; tm < 4; ++tm)
#pragma unroll
        for (int tn = 0; tn < 4; ++tn)
          acc[tm][tn] = __builtin_amdgcn_mfma_f32_16x16x32_f16(
              av[tm], bv[tn], acc[tm][tn], 0, 0, 0);
    }
  }

  float* Pk = P + (size_t)ks * ((size_t)NROWS * 256);
#pragma unroll
  for (int tn = 0; tn < 4; ++tn) {
    const int n = col0 + wc * 64 + tn * 16 + fr;
#pragma unroll
    for (int tm = 0; tm < 4; ++tm) {
      const int rbase = row0 + wr * 64 + tm * 16 + q * 4;
#pragma unroll
      for (int r = 0; r < 4; ++r)
        Pk[(size_t)(rbase + r) * 256 + n] = acc[tm][tn][r];
    }
  }
}

// ---------------------------------------------------------------------------
// Layer 3, atomic fallback (R0-proven): accumulate into out (bias
// pre-applied by prep).
__launch_bounds__(256, 4) __global__
void gemm_out_kernel(const _Float16* __restrict__ A,
                     const _Float16* __restrict__ W,
                     float* __restrict__ out) {
  __shared__ _Float16 Alds[128 * 64];
  __shared__ _Float16 Blds[128 * 64];

  const int tid = threadIdx.x;
  const int lane = tid & 63;
  const int wave = tid >> 6;
  const int wr = wave >> 1;
  const int wc = wave & 1;
  const int row0 = blockIdx.x * 128;
  const int cb = blockIdx.y & 1;
  const int ks = blockIdx.y >> 1;
  const int col0 = cb * 128;
  const int k0b = ks * 832;
  const int k0e = k0b + 832;
  const int lr = lane >> 3;
  const int ls = lane & 7;
  const int lc = ls ^ lr;
  const int fr = lane & 15;
  const int q = lane >> 4;
  const int K = 3328;

  f32x4 acc[4][4] = {};

  for (int k0 = k0b; k0 < k0e; k0 += 64) {
    __syncthreads();
#pragma unroll
    for (int it = 0; it < 4; ++it) {
      const int rl = it * 32 + wave * 8;
      async_cp16(A + (size_t)(row0 + rl + lr) * LDH + k0 + lc * 8,
                 &Alds[rl * 64]);
      async_cp16(W + (size_t)(col0 + rl + lr) * K + k0 + lc * 8,
                 &Blds[rl * 64]);
    }
    __syncthreads();

#pragma unroll
    for (int kq = 0; kq < 2; ++kq) {
      f16x8 av[4], bv[4];
#pragma unroll
      for (int t = 0; t < 4; ++t) {
        const int ra = wr * 64 + t * 16 + fr;
        av[t] = *(const f16x8*)&Alds[ra * 64 + (((q + 4 * kq) ^ (ra & 7)) * 8)];
        const int rb = wc * 64 + t * 16 + fr;
        bv[t] = *(const f16x8*)&Blds[rb * 64 + (((q + 4 * kq) ^ (rb & 7)) * 8)];
      }
#pragma unroll
      for (int tm = 0; tm < 4; ++tm)
#pragma unroll
        for (int tn = 0; tn < 4; ++tn)
          acc[tm][tn] = __builtin_amdgcn_mfma_f32_16x16x32_f16(
              av[tm], bv[tn], acc[tm][tn], 0, 0, 0);
    }
  }

#pragma unroll
  for (int tn = 0; tn < 4; ++tn) {
    const int n = col0 + wc * 64 + tn * 16 + fr;
#pragma unroll
    for (int tm = 0; tm < 4; ++tm) {
      const int rbase = row0 + wr * 64 + tm * 16 + q * 4;
#pragma unroll
      for (int r = 0; r < 4; ++r)
        atomicAdd(&out[(size_t)(rbase + r) * 256 + n], acc[tm][tn][r]);
    }
  }
}

// ---------------------------------------------------------------------------
// ragged segment softmax, in place on out[8192][256]; 4 rows/block (1/wave).
// (atomic-fallback path)
__global__ void segsoftmax_kernel(float* __restrict__ out,
                                  const int* __restrict__ segids) {
  __shared__ float vals[4][256];
  __shared__ float red[4][10];
  const int w = threadIdx.x >> 6;
  const int l = threadIdx.x & 63;
  const int row = blockIdx.x * 4 + w;
  float4 v = *(float4*)&out[(size_t)row * 256 + l * 4];
  *(float4*)&vals[w][l * 4] = v;
  __syncthreads();
  if (l < 10) {
    float m = -1e30f;
    for (int j = c_bnd[l]; j < c_bnd[l + 1]; ++j) m = fmaxf(m, vals[w][j]);
    red[w][l] = m;
  }
  __syncthreads();
  const int4 s4 = *(const int4*)&segids[l * 4];
  float4 e;
  e.x = expf(v.x - red[w][s4.x]);
  e.y = expf(v.y - red[w][s4.y]);
  e.z = expf(v.z - red[w][s4.z]);
  e.w = expf(v.w - red[w][s4.w]);
  *(float4*)&vals[w][l * 4] = e;
  __syncthreads();
  if (l < 10) {
    float s = 0.0f;
    for (int j = c_bnd[l]; j < c_bnd[l + 1]; ++j) s += vals[w][j];
    red[w][l] = s;
  }
  __syncthreads();
  float4 o;
  o.x = e.x / red[w][s4.x];
  o.y = e.y / red[w][s4.y];
  o.z = e.z / red[w][s4.z];
  o.w = e.w / red[w][s4.w];
  *(float4*)&out[(size_t)row * 256 + l * 4] = o;
}

// Partials path: load = sum of 4 splitK partials + bias, then softmax.
__global__ void segsoftmax_sum_kernel(const float* __restrict__ P,
                                      const float* __restrict__ b3,
                                      float* __restrict__ out,
                                      const int* __restrict__ segids) {
  __shared__ float vals[4][256];
  __shared__ float red[4][10];
  const int w = threadIdx.x >> 6;
  const int l = threadIdx.x & 63;
  const int row = blockIdx.x * 4 + w;
  const size_t base = (size_t)row * 256 + l * 4;
  float4 v = *(const float4*)&P[base];
  const float4 v1 = *(const float4*)&P[base + (size_t)1 * NROWS * 256];
  const float4 v2 = *(const float4*)&P[base + (size_t)2 * NROWS * 256];
  const float4 v3 = *(const float4*)&P[base + (size_t)3 * NROWS * 256];
  const float4 b = *(const float4*)&b3[l * 4];
  v.x += v1.x + v2.x + v3.x + b.x;
  v.y += v1.y + v2.y + v3.y + b.y;
  v.z += v1.z + v2.z + v3.z + b.z;
  v.w += v1.w + v2.w + v3.w + b.w;
  *(float4*)&vals[w][l * 4] = v;
  __syncthreads();
  if (l < 10) {
    float m = -1e30f;
    for (int j = c_bnd[l]; j < c_bnd[l + 1]; ++j) m = fmaxf(m, vals[w][j]);
    red[w][l] = m;
  }
  __syncthreads();
  const int4 s4 = *(const int4*)&segids[l * 4];
  float4 e;
  e.x = expf(v.x - red[w][s4.x]);
  e.y = expf(v.y - red[w][s4.y]);
  e.z = expf(v.z - red[w][s4.z]);
  e.w = expf(v.w - red[w][s4.w]);
  *(float4*)&vals[w][l * 4] = e;
  __syncthreads();
  if (l < 10) {
    float s = 0.0f;
    for (int j = c_bnd[l]; j < c_bnd[l + 1]; ++j) s += vals[w][j];
    red[w][l] = s;
  }
  __syncthreads();
  float4 o;
  o.x = e.x / red[w][s4.x];
  o.y = e.y / red[w][s4.y];
  o.z = e.z / red[w][s4.z];
  o.w = e.w / red[w][s4.w];
  *(float4*)&out[(size_t)row * 256 + l * 4] = o;
}

// ---------------------------------------------------------------------------
extern "C" void kernel_launch(void* const* d_in, const int* in_sizes, int n_in,
                              void* d_out, int out_size, void* d_ws,
                              size_t ws_size, hipStream_t stream) {
  const float* x = (const float*)d_in[0];
  const float* W0 = (const float*)d_in[1];
  const float* b0 = (const float*)d_in[2];
  const float* g0 = (const float*)d_in[3];
  const float* be0 = (const float*)d_in[4];
  const float* rm0 = (const float*)d_in[5];
  const float* rv0 = (const float*)d_in[6];
  const float* W1 = (const float*)d_in[7];
  const float* b1 = (const float*)d_in[8];
  const float* g1 = (const float*)d_in[9];
  const float* be1 = (const float*)d_in[10];
  const float* rm1 = (const float*)d_in[11];
  const float* rv1 = (const float*)d_in[12];
  const float* W2 = (const float*)d_in[13];
  const float* b2 = (const float*)d_in[14];
  const float* g2 = (const float*)d_in[15];
  const float* be2 = (const float*)d_in[16];
  const float* rm2 = (const float*)d_in[17];
  const float* rv2 = (const float*)d_in[18];
  const float* W3 = (const float*)d_in[19];
  const float* b3 = (const float*)d_in[20];
  const int* seg = (const int*)d_in[21];
  float* out = (float*)d_out;

  // ws (fp16): H[8192*3328] | Wh0 | Wh1 | Wh2 | Wh3  (61.1 MiB)
  // then (fp32, partials path): P[4][8192][256]  (+32 MiB)
  _Float16* H = (_Float16*)d_ws;
  size_t off = (size_t)NROWS * LDH;
  _Float16* Wh0 = H + off; off += 1024 * 256;
  _Float16* Wh1 = H + off; off += 1024 * 1280;
  _Float16* Wh2 = H + off; off += 1024 * 2304;
  _Float16* Wh3 = H + off; off += 256 * 3328;
  float* P = (float*)(H + off);  // 16B-aligned (off*2 % 16 == 0)
  const size_t need = off * 2 + (size_t)4 * NROWS * 256 * 4;
  const bool partials = ws_size >= need;

  // prep float4 counts: W0 | x | out-init(fallback only)
  const int n0 = 65536, n1 = n0 + 524288, n2 = n1 + 524288;
  const int nprep = partials ? n1 : n2;
  prep_kernel<<<(nprep + 255) / 256, 256, 0, stream>>>(W0, x, b3, Wh0, H, out,
                                                       n0, n1, nprep);

  dim3 blk(256);
  // gemm_bn: 1D grid 512, col0 = bid&7 (XCD-pinned W panels). Tail
  // converts the NEXT consumer's weights.
  gemm_bn_kernel<<<512, blk, 0, stream>>>(
      H + 3072, 256, Wh0, b0, g0, be0, rm0, rv0, H, 2048,
      W1, Wh1, 1024 * 1280 / 4);
  gemm_bn_kernel<<<512, blk, 0, stream>>>(
      H + 2048, 1280, Wh1, b1, g1, be1, rm1, rv1, H, 1024,
      W2, Wh2, 1024 * 2304 / 4);
  gemm_bn_kernel<<<512, blk, 0, stream>>>(
      H + 1024, 2304, Wh2, b2, g2, be2, rm2, rv2, H, 0,
      W3, Wh3, 256 * 3328 / 4);
  if (partials) {
    gemm_out_split<<<dim3(64, 8), blk, 0, stream>>>(H, Wh3, P);
    segsoftmax_sum_kernel<<<2048, 256, 0, stream>>>(P, b3, out, seg);
  } else {
    gemm_out_kernel<<<dim3(64, 8), blk, 0, stream>>>(H, Wh3, out);
    segsoftmax_kernel<<<2048, 256, 0, stream>>>(out, seg);
  }
}

// Round 12
// 237.557 us; speedup vs baseline: 1.3788x; 1.3788x over previous
//
#include <hip/hip_runtime.h>
#include <hip/hip_fp16.h>

// ResidualDenoiser: 4 chained GEMMs + BN/ReLU + ragged segment softmax.
// Activations live in one persistent fp16 buffer H[8192][3328] laid out
// [A3 | A2 | A1 | A0=x] so each layer's concatenated input is H + colOff.
//   layer0: in H+3072 (K= 256) -> out cols 2048:3072  (+ converts Wh1)
//   layer1: in H+2048 (K=1280) -> out cols 1024:2048  (+ converts Wh2)
//   layer2: in H+1024 (K=2304) -> out cols    0:1024  (+ converts Wh3)
//   layer3: in H+0    (K=3328) -> splitK=2; partials to workspace (no
//           atomics), softmax dispatch sums partials + bias.
// LESSONS:
//  R4-R6: in-kernel cross-block sync costs 300-450 us — keep dispatches.
//  R7-R12: 6 failed/neutral GEMM-core re-schedulings. MfmaUtil pinned 33%.
//  R14 (WIN, 243->229): gemm_out atomics -> splitK partials + fused sum.
//  R15 (FAILED) / R16 (NULL): weight-conversion placement — conversion
//    traffic is BW-serial wherever it runs. Tail-converts kept (harmless).
//  R17 (FAILED, 327): B streamed global->reg; FETCH 38->153MB (W panels
//    re-fetched ~24x — XCD-L2 residency assumption wrong at 2 blocks/CU
//    with streaming A evictions). B must go through LDS. Core FROZEN.
//  R18 (this round): splitK 4->2 in gemm_out (last removable traffic):
//    P round-trip 64MB -> 32MB (~-5us BW). Risk: 256 blocks = 1/CU for
//    gemm_out (was 2/CU); if null-or-worse, session plateau at R16.

#define LDH 3328
#define NROWS 8192

typedef _Float16 f16x8 __attribute__((ext_vector_type(8)));
typedef _Float16 f16x4 __attribute__((ext_vector_type(4)));
typedef float f32x4 __attribute__((ext_vector_type(4)));

__constant__ int c_bnd[11] = {0, 2, 5, 10, 18, 31, 52, 86, 141, 230, 256};

// async global->LDS, 16B per lane; LDS dest is wave-uniform base + lane*16.
__device__ __forceinline__ void async_cp16(const _Float16* g, _Float16* l) {
  __builtin_amdgcn_global_load_lds(
      (__attribute__((address_space(1))) void*)g,
      (__attribute__((address_space(3))) void*)l, 16, 0, 0);
}

__device__ __forceinline__ _Float16 f2h(float f) { return (_Float16)f; }

// ---------------------------------------------------------------------------
// prep (slim): W0 fp32->fp16, x staged into H; out=bias on fallback path.
__global__ void prep_kernel(const float* __restrict__ w0,
                            const float* __restrict__ x,
                            const float* __restrict__ b3,
                            _Float16* __restrict__ d0,
                            _Float16* __restrict__ H, float* __restrict__ out,
                            int n0, int n1, int n2) {
  int i = blockIdx.x * blockDim.x + threadIdx.x;
  if (i >= n2) return;
  if (i >= n1) {  // out[8192][256] = broadcast bias b3 (fallback path)
    const int j = i - n1;
    const int c = (j & 63) * 4;
    *(float4*)&out[(size_t)j * 4] = *(const float4*)&b3[c];
    return;
  }
  if (i >= n0) {  // x[8192,256] -> H[:, 3072:3328]
    const int j = i - n0;
    const int row = j >> 6;
    const int c = (j & 63) * 4;
    const float4 v = *(const float4*)&x[(size_t)j * 4];
    f16x4 h = {f2h(v.x), f2h(v.y), f2h(v.z), f2h(v.w)};
    *(f16x4*)&H[(size_t)row * LDH + 3072 + c] = h;
    return;
  }
  const float4 v = *(const float4*)&w0[(size_t)i * 4];
  f16x4 h = {f2h(v.x), f2h(v.y), f2h(v.z), f2h(v.w)};
  *(f16x4*)&d0[(size_t)i * 4] = h;
}

// ---------------------------------------------------------------------------
// Layers 0-2 (R0-proven GEMM body): C = relu(bn(A@W^T)) fp16.
// Grid dim3(64,8). BK=128: LDS tiles 128x128 fp16 (32KB each). Row = 16
// chunks of 16B, chunk c of row r at slot c^(r&7) (XOR swizzle on the
// GLOBAL source address; LDS dest linear).
// POST-EPILOGUE TAIL: all 512 blocks grid-stride-convert the NEXT layer's
// weights fp32->fp16.
__launch_bounds__(256, 2) __global__
void gemm_bn_kernel(const _Float16* __restrict__ A, int K,
                    const _Float16* __restrict__ W,
                    const float* __restrict__ bias,
                    const float* __restrict__ g, const float* __restrict__ be,
                    const float* __restrict__ rm,
                    const float* __restrict__ rv, _Float16* __restrict__ outH,
                    int outOff, const float* __restrict__ cvt_src,
                    _Float16* __restrict__ cvt_dst, int cvt_nf4) {
  __shared__ _Float16 Alds[128 * 128];  // 32 KB
  __shared__ _Float16 Blds[128 * 128];  // 32 KB

  const int tid = threadIdx.x;
  const int lane = tid & 63;
  const int wave = tid >> 6;          // 0..3
  const int wr = wave >> 1;           // 64-row half
  const int wc = wave & 1;            // 64-col half
  const int row0 = blockIdx.x * 128;  // M block
  const int col0 = blockIdx.y * 128;  // N block
  // staging lane decomposition: each cp16 instr covers 4 rows x 16 chunks
  const int lr4 = lane >> 4;  // row within 4-row group
  const int sl = lane & 15;   // lds slot within row
  // fragment lane decomposition (16x16x32 MFMA)
  const int fr = lane & 15;  // m (A) / n (B) index
  const int q = lane >> 4;   // quad: k = q*8 + j

  f32x4 acc[4][4] = {};

  for (int k0 = 0; k0 < K; k0 += 128) {
    __syncthreads();  // previous-iter consumers done before overwrite
#pragma unroll
    for (int it = 0; it < 8; ++it) {
      const int j = it * 4 + wave;     // instr id 0..31
      const int r = j * 4 + lr4;       // tile row 0..127
      const int gc = sl ^ (r & 7);     // global chunk fetched into slot sl
      async_cp16(A + (size_t)(row0 + r) * LDH + k0 + gc * 8, &Alds[j * 512]);
      async_cp16(W + (size_t)(col0 + r) * K + k0 + gc * 8, &Blds[j * 512]);
    }
    __syncthreads();  // drains vmcnt: staging complete

#pragma unroll
    for (int kq = 0; kq < 4; ++kq) {
      f16x8 av[4], bv[4];
#pragma unroll
      for (int t = 0; t < 4; ++t) {
        const int ra = wr * 64 + t * 16 + fr;
        av[t] =
            *(const f16x8*)&Alds[ra * 128 + (((kq * 4 + q) ^ (ra & 7)) * 8)];
        const int rb = wc * 64 + t * 16 + fr;
        bv[t] =
            *(const f16x8*)&Blds[rb * 128 + (((kq * 4 + q) ^ (rb & 7)) * 8)];
      }
#pragma unroll
      for (int tm = 0; tm < 4; ++tm)
#pragma unroll
        for (int tn = 0; tn < 4; ++tn)
          acc[tm][tn] = __builtin_amdgcn_mfma_f32_16x16x32_f16(
              av[tm], bv[tn], acc[tm][tn], 0, 0, 0);
    }
  }

  // Epilogue. C/D layout: col = lane&15, row = (lane>>4)*4 + reg.
#pragma unroll
  for (int tn = 0; tn < 4; ++tn) {
    const int n = col0 + wc * 64 + tn * 16 + fr;
    const float alpha = g[n] * rsqrtf(rv[n] + 1e-5f);
    const float beta = (bias[n] - rm[n]) * alpha + be[n];
#pragma unroll
    for (int tm = 0; tm < 4; ++tm) {
      const int rbase = row0 + wr * 64 + tm * 16 + q * 4;
#pragma unroll
      for (int r = 0; r < 4; ++r) {
        float v = acc[tm][tn][r] * alpha + beta;
        v = fmaxf(v, 0.0f);
        outH[(size_t)(rbase + r) * LDH + outOff + n] = f2h(v);
      }
    }
  }

  // Tail: convert next layer's weights across all 512 blocks.
  const int bid = blockIdx.y * 64 + blockIdx.x;  // 0..511
  for (int i = bid * 256 + tid; i < cvt_nf4; i += 512 * 256) {
    const float4 v = *(const float4*)&cvt_src[(size_t)i * 4];
    f16x4 h = {f2h(v.x), f2h(v.y), f2h(v.z), f2h(v.w)};
    *(f16x4*)&cvt_dst[(size_t)i * 4] = h;
  }
}

// ---------------------------------------------------------------------------
// Layer 3, partials path: splitK=2, BK=64 (1664 = 26*64 per slice). Grid
// dim3(64,4): cb=by&1 (col tile), ks=by>>1 (0..1). Plain stores into
// P[ks][8192][256] fp32 (no atomics).
__launch_bounds__(256, 4) __global__
void gemm_out_split(const _Float16* __restrict__ A,
                    const _Float16* __restrict__ W, float* __restrict__ P) {
  __shared__ _Float16 Alds[128 * 64];
  __shared__ _Float16 Blds[128 * 64];

  const int tid = threadIdx.x;
  const int lane = tid & 63;
  const int wave = tid >> 6;
  const int wr = wave >> 1;
  const int wc = wave & 1;
  const int row0 = blockIdx.x * 128;
  const int cb = blockIdx.y & 1;
  const int ks = blockIdx.y >> 1;
  const int col0 = cb * 128;
  const int k0b = ks * 1664;
  const int k0e = k0b + 1664;
  const int lr = lane >> 3;  // staging: 8 rows x 8 16B-chunks
  const int ls = lane & 7;
  const int lc = ls ^ lr;
  const int fr = lane & 15;
  const int q = lane >> 4;
  const int K = 3328;

  f32x4 acc[4][4] = {};

  for (int k0 = k0b; k0 < k0e; k0 += 64) {
    __syncthreads();
#pragma unroll
    for (int it = 0; it < 4; ++it) {
      const int rl = it * 32 + wave * 8;
      async_cp16(A + (size_t)(row0 + rl + lr) * LDH + k0 + lc * 8,
                 &Alds[rl * 64]);
      async_cp16(W + (size_t)(col0 + rl + lr) * K + k0 + lc * 8,
                 &Blds[rl * 64]);
    }
    __syncthreads();

#pragma unroll
    for (int kq = 0; kq < 2; ++kq) {
      f16x8 av[4], bv[4];
#pragma unroll
      for (int t = 0; t < 4; ++t) {
        const int ra = wr * 64 + t * 16 + fr;
        av[t] = *(const f16x8*)&Alds[ra * 64 + (((q + 4 * kq) ^ (ra & 7)) * 8)];
        const int rb = wc * 64 + t * 16 + fr;
        bv[t] = *(const f16x8*)&Blds[rb * 64 + (((q + 4 * kq) ^ (rb & 7)) * 8)];
      }
#pragma unroll
      for (int tm = 0; tm < 4; ++tm)
#pragma unroll
        for (int tn = 0; tn < 4; ++tn)
          acc[tm][tn] = __builtin_amdgcn_mfma_f32_16x16x32_f16(
              av[tm], bv[tn], acc[tm][tn], 0, 0, 0);
    }
  }

  float* Pk = P + (size_t)ks * ((size_t)NROWS * 256);
#pragma unroll
  for (int tn = 0; tn < 4; ++tn) {
    const int n = col0 + wc * 64 + tn * 16 + fr;
#pragma unroll
    for (int tm = 0; tm < 4; ++tm) {
      const int rbase = row0 + wr * 64 + tm * 16 + q * 4;
#pragma unroll
      for (int r = 0; r < 4; ++r)
        Pk[(size_t)(rbase + r) * 256 + n] = acc[tm][tn][r];
    }
  }
}

// ---------------------------------------------------------------------------
// Layer 3, atomic fallback (R0-proven, splitK=4): accumulate into out
// (bias pre-applied by prep).
__launch_bounds__(256, 4) __global__
void gemm_out_kernel(const _Float16* __restrict__ A,
                     const _Float16* __restrict__ W,
                     float* __restrict__ out) {
  __shared__ _Float16 Alds[128 * 64];
  __shared__ _Float16 Blds[128 * 64];

  const int tid = threadIdx.x;
  const int lane = tid & 63;
  const int wave = tid >> 6;
  const int wr = wave >> 1;
  const int wc = wave & 1;
  const int row0 = blockIdx.x * 128;
  const int cb = blockIdx.y & 1;
  const int ks = blockIdx.y >> 1;
  const int col0 = cb * 128;
  const int k0b = ks * 832;
  const int k0e = k0b + 832;
  const int lr = lane >> 3;
  const int ls = lane & 7;
  const int lc = ls ^ lr;
  const int fr = lane & 15;
  const int q = lane >> 4;
  const int K = 3328;

  f32x4 acc[4][4] = {};

  for (int k0 = k0b; k0 < k0e; k0 += 64) {
    __syncthreads();
#pragma unroll
    for (int it = 0; it < 4; ++it) {
      const int rl = it * 32 + wave * 8;
      async_cp16(A + (size_t)(row0 + rl + lr) * LDH + k0 + lc * 8,
                 &Alds[rl * 64]);
      async_cp16(W + (size_t)(col0 + rl + lr) * K + k0 + lc * 8,
                 &Blds[rl * 64]);
    }
    __syncthreads();

#pragma unroll
    for (int kq = 0; kq < 2; ++kq) {
      f16x8 av[4], bv[4];
#pragma unroll
      for (int t = 0; t < 4; ++t) {
        const int ra = wr * 64 + t * 16 + fr;
        av[t] = *(const f16x8*)&Alds[ra * 64 + (((q + 4 * kq) ^ (ra & 7)) * 8)];
        const int rb = wc * 64 + t * 16 + fr;
        bv[t] = *(const f16x8*)&Blds[rb * 64 + (((q + 4 * kq) ^ (rb & 7)) * 8)];
      }
#pragma unroll
      for (int tm = 0; tm < 4; ++tm)
#pragma unroll
        for (int tn = 0; tn < 4; ++tn)
          acc[tm][tn] = __builtin_amdgcn_mfma_f32_16x16x32_f16(
              av[tm], bv[tn], acc[tm][tn], 0, 0, 0);
    }
  }

#pragma unroll
  for (int tn = 0; tn < 4; ++tn) {
    const int n = col0 + wc * 64 + tn * 16 + fr;
#pragma unroll
    for (int tm = 0; tm < 4; ++tm) {
      const int rbase = row0 + wr * 64 + tm * 16 + q * 4;
#pragma unroll
      for (int r = 0; r < 4; ++r)
        atomicAdd(&out[(size_t)(rbase + r) * 256 + n], acc[tm][tn][r]);
    }
  }
}

// ---------------------------------------------------------------------------
// ragged segment softmax, in place on out[8192][256]; 4 rows/block (1/wave).
// (atomic-fallback path)
__global__ void segsoftmax_kernel(float* __restrict__ out,
                                  const int* __restrict__ segids) {
  __shared__ float vals[4][256];
  __shared__ float red[4][10];
  const int w = threadIdx.x >> 6;
  const int l = threadIdx.x & 63;
  const int row = blockIdx.x * 4 + w;
  float4 v = *(float4*)&out[(size_t)row * 256 + l * 4];
  *(float4*)&vals[w][l * 4] = v;
  __syncthreads();
  if (l < 10) {
    float m = -1e30f;
    for (int j = c_bnd[l]; j < c_bnd[l + 1]; ++j) m = fmaxf(m, vals[w][j]);
    red[w][l] = m;
  }
  __syncthreads();
  const int4 s4 = *(const int4*)&segids[l * 4];
  float4 e;
  e.x = expf(v.x - red[w][s4.x]);
  e.y = expf(v.y - red[w][s4.y]);
  e.z = expf(v.z - red[w][s4.z]);
  e.w = expf(v.w - red[w][s4.w]);
  *(float4*)&vals[w][l * 4] = e;
  __syncthreads();
  if (l < 10) {
    float s = 0.0f;
    for (int j = c_bnd[l]; j < c_bnd[l + 1]; ++j) s += vals[w][j];
    red[w][l] = s;
  }
  __syncthreads();
  float4 o;
  o.x = e.x / red[w][s4.x];
  o.y = e.y / red[w][s4.y];
  o.z = e.z / red[w][s4.z];
  o.w = e.w / red[w][s4.w];
  *(float4*)&out[(size_t)row * 256 + l * 4] = o;
}

// Partials path: load = sum of 2 splitK partials + bias, then softmax.
__global__ void segsoftmax_sum_kernel(const float* __restrict__ P,
                                      const float* __restrict__ b3,
                                      float* __restrict__ out,
                                      const int* __restrict__ segids) {
  __shared__ float vals[4][256];
  __shared__ float red[4][10];
  const int w = threadIdx.x >> 6;
  const int l = threadIdx.x & 63;
  const int row = blockIdx.x * 4 + w;
  const size_t base = (size_t)row * 256 + l * 4;
  float4 v = *(const float4*)&P[base];
  const float4 v1 = *(const float4*)&P[base + (size_t)1 * NROWS * 256];
  const float4 b = *(const float4*)&b3[l * 4];
  v.x += v1.x + b.x;
  v.y += v1.y + b.y;
  v.z += v1.z + b.z;
  v.w += v1.w + b.w;
  *(float4*)&vals[w][l * 4] = v;
  __syncthreads();
  if (l < 10) {
    float m = -1e30f;
    for (int j = c_bnd[l]; j < c_bnd[l + 1]; ++j) m = fmaxf(m, vals[w][j]);
    red[w][l] = m;
  }
  __syncthreads();
  const int4 s4 = *(const int4*)&segids[l * 4];
  float4 e;
  e.x = expf(v.x - red[w][s4.x]);
  e.y = expf(v.y - red[w][s4.y]);
  e.z = expf(v.z - red[w][s4.z]);
  e.w = expf(v.w - red[w][s4.w]);
  *(float4*)&vals[w][l * 4] = e;
  __syncthreads();
  if (l < 10) {
    float s = 0.0f;
    for (int j = c_bnd[l]; j < c_bnd[l + 1]; ++j) s += vals[w][j];
    red[w][l] = s;
  }
  __syncthreads();
  float4 o;
  o.x = e.x / red[w][s4.x];
  o.y = e.y / red[w][s4.y];
  o.z = e.z / red[w][s4.z];
  o.w = e.w / red[w][s4.w];
  *(float4*)&out[(size_t)row * 256 + l * 4] = o;
}

// ---------------------------------------------------------------------------
extern "C" void kernel_launch(void* const* d_in, const int* in_sizes, int n_in,
                              void* d_out, int out_size, void* d_ws,
                              size_t ws_size, hipStream_t stream) {
  const float* x = (const float*)d_in[0];
  const float* W0 = (const float*)d_in[1];
  const float* b0 = (const float*)d_in[2];
  const float* g0 = (const float*)d_in[3];
  const float* be0 = (const float*)d_in[4];
  const float* rm0 = (const float*)d_in[5];
  const float* rv0 = (const float*)d_in[6];
  const float* W1 = (const float*)d_in[7];
  const float* b1 = (const float*)d_in[8];
  const float* g1 = (const float*)d_in[9];
  const float* be1 = (const float*)d_in[10];
  const float* rm1 = (const float*)d_in[11];
  const float* rv1 = (const float*)d_in[12];
  const float* W2 = (const float*)d_in[13];
  const float* b2 = (const float*)d_in[14];
  const float* g2 = (const float*)d_in[15];
  const float* be2 = (const float*)d_in[16];
  const float* rm2 = (const float*)d_in[17];
  const float* rv2 = (const float*)d_in[18];
  const float* W3 = (const float*)d_in[19];
  const float* b3 = (const float*)d_in[20];
  const int* seg = (const int*)d_in[21];
  float* out = (float*)d_out;

  // ws (fp16): H[8192*3328] | Wh0 | Wh1 | Wh2 | Wh3  (61.1 MiB)
  // then (fp32, partials path): P[2][8192][256]  (+16 MiB)
  _Float16* H = (_Float16*)d_ws;
  size_t off = (size_t)NROWS * LDH;
  _Float16* Wh0 = H + off; off += 1024 * 256;
  _Float16* Wh1 = H + off; off += 1024 * 1280;
  _Float16* Wh2 = H + off; off += 1024 * 2304;
  _Float16* Wh3 = H + off; off += 256 * 3328;
  float* P = (float*)(H + off);  // 16B-aligned (off*2 % 16 == 0)
  const size_t need = off * 2 + (size_t)2 * NROWS * 256 * 4;
  const bool partials = ws_size >= need;

  // prep float4 counts: W0 | x | out-init(fallback only)
  const int n0 = 65536, n1 = n0 + 524288, n2 = n1 + 524288;
  const int nprep = partials ? n1 : n2;
  prep_kernel<<<(nprep + 255) / 256, 256, 0, stream>>>(W0, x, b3, Wh0, H, out,
                                                       n0, n1, nprep);

  dim3 blk(256);
  // Each gemm dispatch tail-converts the NEXT consumer's weights (512
  // blocks grid-stride).
  gemm_bn_kernel<<<dim3(64, 8), blk, 0, stream>>>(
      H + 3072, 256, Wh0, b0, g0, be0, rm0, rv0, H, 2048,
      W1, Wh1, 1024 * 1280 / 4);
  gemm_bn_kernel<<<dim3(64, 8), blk, 0, stream>>>(
      H + 2048, 1280, Wh1, b1, g1, be1, rm1, rv1, H, 1024,
      W2, Wh2, 1024 * 2304 / 4);
  gemm_bn_kernel<<<dim3(64, 8), blk, 0, stream>>>(
      H + 1024, 2304, Wh2, b2, g2, be2, rm2, rv2, H, 0,
      W3, Wh3, 256 * 3328 / 4);
  if (partials) {
    gemm_out_split<<<dim3(64, 4), blk, 0, stream>>>(H, Wh3, P);
    segsoftmax_sum_kernel<<<2048, 256, 0, stream>>>(P, b3, out, seg);
  } else {
    gemm_out_kernel<<<dim3(64, 8), blk, 0, stream>>>(H, Wh3, out);
    segsoftmax_kernel<<<2048, 256, 0, stream>>>(out, seg);
  }
}

// Round 13
// 227.642 us; speedup vs baseline: 1.4388x; 1.0436x over previous
//
#include <hip/hip_runtime.h>
#include <hip/hip_fp16.h>

// ResidualDenoiser: 4 chained GEMMs + BN/ReLU + ragged segment softmax.
// Activations live in one persistent fp16 buffer H[8192][3328] laid out
// [A3 | A2 | A1 | A0=x] so each layer's concatenated input is H + colOff.
//   layer0: in H+3072 (K= 256) -> out cols 2048:3072  (+ converts Wh1)
//   layer1: in H+2048 (K=1280) -> out cols 1024:2048  (+ converts Wh2)
//   layer2: in H+1024 (K=2304) -> out cols    0:1024  (+ converts Wh3)
//   layer3: in H+0    (K=3328) -> splitK=4; partials to workspace (no
//           atomics), softmax dispatch sums partials + bias.
// LESSONS (final state: R16 configuration, 229.3us, twice reproduced):
//  R4-R6: in-kernel cross-block sync costs 300-450 us — keep dispatches.
//  R7-R12: 6 failed/neutral GEMM-core re-schedulings. MfmaUtil pinned 33%;
//    LDS and MFMA phases serialize within a block in every structure
//    tried; only co-resident blocks provide overlap.
//  R14 (WIN, 243->229): gemm_out atomics -> splitK partials + fused sum.
//  R15 (FAILED) / R16 (NULL): weight-conversion placement — conversion
//    traffic is BW-serial wherever it runs. Tail-converts kept (harmless).
//  R17 (FAILED, 327): B streamed global->reg; W panels re-fetched ~24x
//    (FETCH 38->153MB). B must go through LDS.
//  R18 (FAILED, 237): splitK 4->2 dropped gemm_out to 1 block/CU; lost
//    block-level overlap (~13us) > BW saved (~5us). NEVER trade block
//    concurrency for traffic on this kernel family.

#define LDH 3328
#define NROWS 8192

typedef _Float16 f16x8 __attribute__((ext_vector_type(8)));
typedef _Float16 f16x4 __attribute__((ext_vector_type(4)));
typedef float f32x4 __attribute__((ext_vector_type(4)));

__constant__ int c_bnd[11] = {0, 2, 5, 10, 18, 31, 52, 86, 141, 230, 256};

// async global->LDS, 16B per lane; LDS dest is wave-uniform base + lane*16.
__device__ __forceinline__ void async_cp16(const _Float16* g, _Float16* l) {
  __builtin_amdgcn_global_load_lds(
      (__attribute__((address_space(1))) void*)g,
      (__attribute__((address_space(3))) void*)l, 16, 0, 0);
}

__device__ __forceinline__ _Float16 f2h(float f) { return (_Float16)f; }

// ---------------------------------------------------------------------------
// prep (slim): W0 fp32->fp16, x staged into H; out=bias on fallback path.
__global__ void prep_kernel(const float* __restrict__ w0,
                            const float* __restrict__ x,
                            const float* __restrict__ b3,
                            _Float16* __restrict__ d0,
                            _Float16* __restrict__ H, float* __restrict__ out,
                            int n0, int n1, int n2) {
  int i = blockIdx.x * blockDim.x + threadIdx.x;
  if (i >= n2) return;
  if (i >= n1) {  // out[8192][256] = broadcast bias b3 (fallback path)
    const int j = i - n1;
    const int c = (j & 63) * 4;
    *(float4*)&out[(size_t)j * 4] = *(const float4*)&b3[c];
    return;
  }
  if (i >= n0) {  // x[8192,256] -> H[:, 3072:3328]
    const int j = i - n0;
    const int row = j >> 6;
    const int c = (j & 63) * 4;
    const float4 v = *(const float4*)&x[(size_t)j * 4];
    f16x4 h = {f2h(v.x), f2h(v.y), f2h(v.z), f2h(v.w)};
    *(f16x4*)&H[(size_t)row * LDH + 3072 + c] = h;
    return;
  }
  const float4 v = *(const float4*)&w0[(size_t)i * 4];
  f16x4 h = {f2h(v.x), f2h(v.y), f2h(v.z), f2h(v.w)};
  *(f16x4*)&d0[(size_t)i * 4] = h;
}

// ---------------------------------------------------------------------------
// Layers 0-2 (R0-proven GEMM body): C = relu(bn(A@W^T)) fp16.
// Grid dim3(64,8). BK=128: LDS tiles 128x128 fp16 (32KB each). Row = 16
// chunks of 16B, chunk c of row r at slot c^(r&7) (XOR swizzle on the
// GLOBAL source address; LDS dest linear).
// POST-EPILOGUE TAIL: all 512 blocks grid-stride-convert the NEXT layer's
// weights fp32->fp16.
__launch_bounds__(256, 2) __global__
void gemm_bn_kernel(const _Float16* __restrict__ A, int K,
                    const _Float16* __restrict__ W,
                    const float* __restrict__ bias,
                    const float* __restrict__ g, const float* __restrict__ be,
                    const float* __restrict__ rm,
                    const float* __restrict__ rv, _Float16* __restrict__ outH,
                    int outOff, const float* __restrict__ cvt_src,
                    _Float16* __restrict__ cvt_dst, int cvt_nf4) {
  __shared__ _Float16 Alds[128 * 128];  // 32 KB
  __shared__ _Float16 Blds[128 * 128];  // 32 KB

  const int tid = threadIdx.x;
  const int lane = tid & 63;
  const int wave = tid >> 6;          // 0..3
  const int wr = wave >> 1;           // 64-row half
  const int wc = wave & 1;            // 64-col half
  const int row0 = blockIdx.x * 128;  // M block
  const int col0 = blockIdx.y * 128;  // N block
  // staging lane decomposition: each cp16 instr covers 4 rows x 16 chunks
  const int lr4 = lane >> 4;  // row within 4-row group
  const int sl = lane & 15;   // lds slot within row
  // fragment lane decomposition (16x16x32 MFMA)
  const int fr = lane & 15;  // m (A) / n (B) index
  const int q = lane >> 4;   // quad: k = q*8 + j

  f32x4 acc[4][4] = {};

  for (int k0 = 0; k0 < K; k0 += 128) {
    __syncthreads();  // previous-iter consumers done before overwrite
#pragma unroll
    for (int it = 0; it < 8; ++it) {
      const int j = it * 4 + wave;     // instr id 0..31
      const int r = j * 4 + lr4;       // tile row 0..127
      const int gc = sl ^ (r & 7);     // global chunk fetched into slot sl
      async_cp16(A + (size_t)(row0 + r) * LDH + k0 + gc * 8, &Alds[j * 512]);
      async_cp16(W + (size_t)(col0 + r) * K + k0 + gc * 8, &Blds[j * 512]);
    }
    __syncthreads();  // drains vmcnt: staging complete

#pragma unroll
    for (int kq = 0; kq < 4; ++kq) {
      f16x8 av[4], bv[4];
#pragma unroll
      for (int t = 0; t < 4; ++t) {
        const int ra = wr * 64 + t * 16 + fr;
        av[t] =
            *(const f16x8*)&Alds[ra * 128 + (((kq * 4 + q) ^ (ra & 7)) * 8)];
        const int rb = wc * 64 + t * 16 + fr;
        bv[t] =
            *(const f16x8*)&Blds[rb * 128 + (((kq * 4 + q) ^ (rb & 7)) * 8)];
      }
#pragma unroll
      for (int tm = 0; tm < 4; ++tm)
#pragma unroll
        for (int tn = 0; tn < 4; ++tn)
          acc[tm][tn] = __builtin_amdgcn_mfma_f32_16x16x32_f16(
              av[tm], bv[tn], acc[tm][tn], 0, 0, 0);
    }
  }

  // Epilogue. C/D layout: col = lane&15, row = (lane>>4)*4 + reg.
#pragma unroll
  for (int tn = 0; tn < 4; ++tn) {
    const int n = col0 + wc * 64 + tn * 16 + fr;
    const float alpha = g[n] * rsqrtf(rv[n] + 1e-5f);
    const float beta = (bias[n] - rm[n]) * alpha + be[n];
#pragma unroll
    for (int tm = 0; tm < 4; ++tm) {
      const int rbase = row0 + wr * 64 + tm * 16 + q * 4;
#pragma unroll
      for (int r = 0; r < 4; ++r) {
        float v = acc[tm][tn][r] * alpha + beta;
        v = fmaxf(v, 0.0f);
        outH[(size_t)(rbase + r) * LDH + outOff + n] = f2h(v);
      }
    }
  }

  // Tail: convert next layer's weights across all 512 blocks.
  const int bid = blockIdx.y * 64 + blockIdx.x;  // 0..511
  for (int i = bid * 256 + tid; i < cvt_nf4; i += 512 * 256) {
    const float4 v = *(const float4*)&cvt_src[(size_t)i * 4];
    f16x4 h = {f2h(v.x), f2h(v.y), f2h(v.z), f2h(v.w)};
    *(f16x4*)&cvt_dst[(size_t)i * 4] = h;
  }
}

// ---------------------------------------------------------------------------
// Layer 3, partials path: splitK=4, BK=64. Grid dim3(64,8): cb=by&1 (col
// tile), ks=by>>1. Plain stores into P[ks][8192][256] fp32 (no atomics).
__launch_bounds__(256, 4) __global__
void gemm_out_split(const _Float16* __restrict__ A,
                    const _Float16* __restrict__ W, float* __restrict__ P) {
  __shared__ _Float16 Alds[128 * 64];
  __shared__ _Float16 Blds[128 * 64];

  const int tid = threadIdx.x;
  const int lane = tid & 63;
  const int wave = tid >> 6;
  const int wr = wave >> 1;
  const int wc = wave & 1;
  const int row0 = blockIdx.x * 128;
  const int cb = blockIdx.y & 1;
  const int ks = blockIdx.y >> 1;
  const int col0 = cb * 128;
  const int k0b = ks * 832;
  const int k0e = k0b + 832;
  const int lr = lane >> 3;  // staging: 8 rows x 8 16B-chunks
  const int ls = lane & 7;
  const int lc = ls ^ lr;
  const int fr = lane & 15;
  const int q = lane >> 4;
  const int K = 3328;

  f32x4 acc[4][4] = {};

  for (int k0 = k0b; k0 < k0e; k0 += 64) {
    __syncthreads();
#pragma unroll
    for (int it = 0; it < 4; ++it) {
      const int rl = it * 32 + wave * 8;
      async_cp16(A + (size_t)(row0 + rl + lr) * LDH + k0 + lc * 8,
                 &Alds[rl * 64]);
      async_cp16(W + (size_t)(col0 + rl + lr) * K + k0 + lc * 8,
                 &Blds[rl * 64]);
    }
    __syncthreads();

#pragma unroll
    for (int kq = 0; kq < 2; ++kq) {
      f16x8 av[4], bv[4];
#pragma unroll
      for (int t = 0; t < 4; ++t) {
        const int ra = wr * 64 + t * 16 + fr;
        av[t] = *(const f16x8*)&Alds[ra * 64 + (((q + 4 * kq) ^ (ra & 7)) * 8)];
        const int rb = wc * 64 + t * 16 + fr;
        bv[t] = *(const f16x8*)&Blds[rb * 64 + (((q + 4 * kq) ^ (rb & 7)) * 8)];
      }
#pragma unroll
      for (int tm = 0; tm < 4; ++tm)
#pragma unroll
        for (int tn = 0; tn < 4; ++tn)
          acc[tm][tn] = __builtin_amdgcn_mfma_f32_16x16x32_f16(
              av[tm], bv[tn], acc[tm][tn], 0, 0, 0);
    }
  }

  float* Pk = P + (size_t)ks * ((size_t)NROWS * 256);
#pragma unroll
  for (int tn = 0; tn < 4; ++tn) {
    const int n = col0 + wc * 64 + tn * 16 + fr;
#pragma unroll
    for (int tm = 0; tm < 4; ++tm) {
      const int rbase = row0 + wr * 64 + tm * 16 + q * 4;
#pragma unroll
      for (int r = 0; r < 4; ++r)
        Pk[(size_t)(rbase + r) * 256 + n] = acc[tm][tn][r];
    }
  }
}

// ---------------------------------------------------------------------------
// Layer 3, atomic fallback (R0-proven): accumulate into out (bias
// pre-applied by prep).
__launch_bounds__(256, 4) __global__
void gemm_out_kernel(const _Float16* __restrict__ A,
                     const _Float16* __restrict__ W,
                     float* __restrict__ out) {
  __shared__ _Float16 Alds[128 * 64];
  __shared__ _Float16 Blds[128 * 64];

  const int tid = threadIdx.x;
  const int lane = tid & 63;
  const int wave = tid >> 6;
  const int wr = wave >> 1;
  const int wc = wave & 1;
  const int row0 = blockIdx.x * 128;
  const int cb = blockIdx.y & 1;
  const int ks = blockIdx.y >> 1;
  const int col0 = cb * 128;
  const int k0b = ks * 832;
  const int k0e = k0b + 832;
  const int lr = lane >> 3;
  const int ls = lane & 7;
  const int lc = ls ^ lr;
  const int fr = lane & 15;
  const int q = lane >> 4;
  const int K = 3328;

  f32x4 acc[4][4] = {};

  for (int k0 = k0b; k0 < k0e; k0 += 64) {
    __syncthreads();
#pragma unroll
    for (int it = 0; it < 4; ++it) {
      const int rl = it * 32 + wave * 8;
      async_cp16(A + (size_t)(row0 + rl + lr) * LDH + k0 + lc * 8,
                 &Alds[rl * 64]);
      async_cp16(W + (size_t)(col0 + rl + lr) * K + k0 + lc * 8,
                 &Blds[rl * 64]);
    }
    __syncthreads();

#pragma unroll
    for (int kq = 0; kq < 2; ++kq) {
      f16x8 av[4], bv[4];
#pragma unroll
      for (int t = 0; t < 4; ++t) {
        const int ra = wr * 64 + t * 16 + fr;
        av[t] = *(const f16x8*)&Alds[ra * 64 + (((q + 4 * kq) ^ (ra & 7)) * 8)];
        const int rb = wc * 64 + t * 16 + fr;
        bv[t] = *(const f16x8*)&Blds[rb * 64 + (((q + 4 * kq) ^ (rb & 7)) * 8)];
      }
#pragma unroll
      for (int tm = 0; tm < 4; ++tm)
#pragma unroll
        for (int tn = 0; tn < 4; ++tn)
          acc[tm][tn] = __builtin_amdgcn_mfma_f32_16x16x32_f16(
              av[tm], bv[tn], acc[tm][tn], 0, 0, 0);
    }
  }

#pragma unroll
  for (int tn = 0; tn < 4; ++tn) {
    const int n = col0 + wc * 64 + tn * 16 + fr;
#pragma unroll
    for (int tm = 0; tm < 4; ++tm) {
      const int rbase = row0 + wr * 64 + tm * 16 + q * 4;
#pragma unroll
      for (int r = 0; r < 4; ++r)
        atomicAdd(&out[(size_t)(rbase + r) * 256 + n], acc[tm][tn][r]);
    }
  }
}

// ---------------------------------------------------------------------------
// ragged segment softmax, in place on out[8192][256]; 4 rows/block (1/wave).
// (atomic-fallback path)
__global__ void segsoftmax_kernel(float* __restrict__ out,
                                  const int* __restrict__ segids) {
  __shared__ float vals[4][256];
  __shared__ float red[4][10];
  const int w = threadIdx.x >> 6;
  const int l = threadIdx.x & 63;
  const int row = blockIdx.x * 4 + w;
  float4 v = *(float4*)&out[(size_t)row * 256 + l * 4];
  *(float4*)&vals[w][l * 4] = v;
  __syncthreads();
  if (l < 10) {
    float m = -1e30f;
    for (int j = c_bnd[l]; j < c_bnd[l + 1]; ++j) m = fmaxf(m, vals[w][j]);
    red[w][l] = m;
  }
  __syncthreads();
  const int4 s4 = *(const int4*)&segids[l * 4];
  float4 e;
  e.x = expf(v.x - red[w][s4.x]);
  e.y = expf(v.y - red[w][s4.y]);
  e.z = expf(v.z - red[w][s4.z]);
  e.w = expf(v.w - red[w][s4.w]);
  *(float4*)&vals[w][l * 4] = e;
  __syncthreads();
  if (l < 10) {
    float s = 0.0f;
    for (int j = c_bnd[l]; j < c_bnd[l + 1]; ++j) s += vals[w][j];
    red[w][l] = s;
  }
  __syncthreads();
  float4 o;
  o.x = e.x / red[w][s4.x];
  o.y = e.y / red[w][s4.y];
  o.z = e.z / red[w][s4.z];
  o.w = e.w / red[w][s4.w];
  *(float4*)&out[(size_t)row * 256 + l * 4] = o;
}

// Partials path: load = sum of 4 splitK partials + bias, then softmax.
__global__ void segsoftmax_sum_kernel(const float* __restrict__ P,
                                      const float* __restrict__ b3,
                                      float* __restrict__ out,
                                      const int* __restrict__ segids) {
  __shared__ float vals[4][256];
  __shared__ float red[4][10];
  const int w = threadIdx.x >> 6;
  const int l = threadIdx.x & 63;
  const int row = blockIdx.x * 4 + w;
  const size_t base = (size_t)row * 256 + l * 4;
  float4 v = *(const float4*)&P[base];
  const float4 v1 = *(const float4*)&P[base + (size_t)1 * NROWS * 256];
  const float4 v2 = *(const float4*)&P[base + (size_t)2 * NROWS * 256];
  const float4 v3 = *(const float4*)&P[base + (size_t)3 * NROWS * 256];
  const float4 b = *(const float4*)&b3[l * 4];
  v.x += v1.x + v2.x + v3.x + b.x;
  v.y += v1.y + v2.y + v3.y + b.y;
  v.z += v1.z + v2.z + v3.z + b.z;
  v.w += v1.w + v2.w + v3.w + b.w;
  *(float4*)&vals[w][l * 4] = v;
  __syncthreads();
  if (l < 10) {
    float m = -1e30f;
    for (int j = c_bnd[l]; j < c_bnd[l + 1]; ++j) m = fmaxf(m, vals[w][j]);
    red[w][l] = m;
  }
  __syncthreads();
  const int4 s4 = *(const int4*)&segids[l * 4];
  float4 e;
  e.x = expf(v.x - red[w][s4.x]);
  e.y = expf(v.y - red[w][s4.y]);
  e.z = expf(v.z - red[w][s4.z]);
  e.w = expf(v.w - red[w][s4.w]);
  *(float4*)&vals[w][l * 4] = e;
  __syncthreads();
  if (l < 10) {
    float s = 0.0f;
    for (int j = c_bnd[l]; j < c_bnd[l + 1]; ++j) s += vals[w][j];
    red[w][l] = s;
  }
  __syncthreads();
  float4 o;
  o.x = e.x / red[w][s4.x];
  o.y = e.y / red[w][s4.y];
  o.z = e.z / red[w][s4.z];
  o.w = e.w / red[w][s4.w];
  *(float4*)&out[(size_t)row * 256 + l * 4] = o;
}

// ---------------------------------------------------------------------------
extern "C" void kernel_launch(void* const* d_in, const int* in_sizes, int n_in,
                              void* d_out, int out_size, void* d_ws,
                              size_t ws_size, hipStream_t stream) {
  const float* x = (const float*)d_in[0];
  const float* W0 = (const float*)d_in[1];
  const float* b0 = (const float*)d_in[2];
  const float* g0 = (const float*)d_in[3];
  const float* be0 = (const float*)d_in[4];
  const float* rm0 = (const float*)d_in[5];
  const float* rv0 = (const float*)d_in[6];
  const float* W1 = (const float*)d_in[7];
  const float* b1 = (const float*)d_in[8];
  const float* g1 = (const float*)d_in[9];
  const float* be1 = (const float*)d_in[10];
  const float* rm1 = (const float*)d_in[11];
  const float* rv1 = (const float*)d_in[12];
  const float* W2 = (const float*)d_in[13];
  const float* b2 = (const float*)d_in[14];
  const float* g2 = (const float*)d_in[15];
  const float* be2 = (const float*)d_in[16];
  const float* rm2 = (const float*)d_in[17];
  const float* rv2 = (const float*)d_in[18];
  const float* W3 = (const float*)d_in[19];
  const float* b3 = (const float*)d_in[20];
  const int* seg = (const int*)d_in[21];
  float* out = (float*)d_out;

  // ws (fp16): H[8192*3328] | Wh0 | Wh1 | Wh2 | Wh3  (61.1 MiB)
  // then (fp32, partials path): P[4][8192][256]  (+32 MiB)
  _Float16* H = (_Float16*)d_ws;
  size_t off = (size_t)NROWS * LDH;
  _Float16* Wh0 = H + off; off += 1024 * 256;
  _Float16* Wh1 = H + off; off += 1024 * 1280;
  _Float16* Wh2 = H + off; off += 1024 * 2304;
  _Float16* Wh3 = H + off; off += 256 * 3328;
  float* P = (float*)(H + off);  // 16B-aligned (off*2 % 16 == 0)
  const size_t need = off * 2 + (size_t)4 * NROWS * 256 * 4;
  const bool partials = ws_size >= need;

  // prep float4 counts: W0 | x | out-init(fallback only)
  const int n0 = 65536, n1 = n0 + 524288, n2 = n1 + 524288;
  const int nprep = partials ? n1 : n2;
  prep_kernel<<<(nprep + 255) / 256, 256, 0, stream>>>(W0, x, b3, Wh0, H, out,
                                                       n0, n1, nprep);

  dim3 blk(256);
  // Each gemm dispatch tail-converts the NEXT consumer's weights (512
  // blocks grid-stride).
  gemm_bn_kernel<<<dim3(64, 8), blk, 0, stream>>>(
      H + 3072, 256, Wh0, b0, g0, be0, rm0, rv0, H, 2048,
      W1, Wh1, 1024 * 1280 / 4);
  gemm_bn_kernel<<<dim3(64, 8), blk, 0, stream>>>(
      H + 2048, 1280, Wh1, b1, g1, be1, rm1, rv1, H, 1024,
      W2, Wh2, 1024 * 2304 / 4);
  gemm_bn_kernel<<<dim3(64, 8), blk, 0, stream>>>(
      H + 1024, 2304, Wh2, b2, g2, be2, rm2, rv2, H, 0,
      W3, Wh3, 256 * 3328 / 4);
  if (partials) {
    gemm_out_split<<<dim3(64, 8), blk, 0, stream>>>(H, Wh3, P);
    segsoftmax_sum_kernel<<<2048, 256, 0, stream>>>(P, b3, out, seg);
  } else {
    gemm_out_kernel<<<dim3(64, 8), blk, 0, stream>>>(H, Wh3, out);
    segsoftmax_kernel<<<2048, 256, 0, stream>>>(out, seg);
  }
}